// Round 1
// baseline (7168.850 us; speedup 1.0000x reference)
//
#include <hip/hip_runtime.h>
#include <cstddef>

// Problem constants
#define Bsz  4096
#define Sseq 16
#define Gdim 128
#define Edim 256
#define Hdim 512
#define H4   2048
#define Psteps 16

// ---------------------------------------------------------------------------
// Fold kernel: encE = enc_Wih @ emb_W  (2048x128), decE = dec_Wih @ emb_W,
//              v0b[o] = dec_b[o] + sum_e dec_Wih[o,e]*dec_input0[e]
// ---------------------------------------------------------------------------
__global__ void fold_kernel(const float* __restrict__ encWih,
                            const float* __restrict__ decWih,
                            const float* __restrict__ embW,
                            const float* __restrict__ dec_b,
                            const float* __restrict__ dec0,
                            float* __restrict__ encE,
                            float* __restrict__ decE,
                            float* __restrict__ v0b) {
    const int o = blockIdx.x;    // 0..2047
    const int g = threadIdx.x;   // 0..127
    float se = 0.f, sd = 0.f;
    for (int e = 0; e < Edim; ++e) {
        float w = embW[e * Gdim + g];
        se += encWih[(size_t)o * Edim + e] * w;
        sd += decWih[(size_t)o * Edim + e] * w;
    }
    encE[(size_t)o * Gdim + g] = se;
    decE[(size_t)o * Gdim + g] = sd;
    if (g == 0) {
        float s = dec_b[o];
        for (int e = 0; e < Edim; ++e) s += decWih[(size_t)o * Edim + e] * dec0[e];
        v0b[o] = s;
    }
}

// ---------------------------------------------------------------------------
// Fused GEMM: C[N x Mo] = bias + A1 @ W1^T + A2 @ W2^T   (fp32, row-major)
// A1 row n base = A1 + n*lda1 + (gather ? gather[n]*gmul : 0)
// BM=128 x BN=64 tile, BK=16, 256 threads, 8x4 accum per thread.
// All dims here are exact multiples (N=4096, Mo in {512,2048}, K in {128,512}).
// ---------------------------------------------------------------------------
#define BM 128
#define BN 64
#define BK 16
#define LDA_S 132   // padded LDS pitch (2-way bank alias only -> free)
#define LDB_S 68

__global__ __launch_bounds__(256, 2) void gemm_fused(
    const float* __restrict__ A1, int lda1, int K1, const float* __restrict__ W1,
    const int* __restrict__ gather, int gmul,
    const float* __restrict__ A2, int lda2, int K2, const float* __restrict__ W2,
    const float* __restrict__ bias, float* __restrict__ C, int ldc)
{
    __shared__ float As[BK * LDA_S];
    __shared__ float Bs[BK * LDB_S];
    const int tid = threadIdx.x;
    const int tx = tid & 15;          // col quad   (4 cols)
    const int ty = tid >> 4;          // row octet  (8 rows)
    const int rowBase = blockIdx.y * BM;
    const int colBase = blockIdx.x * BN;
    const int lrow = tid >> 2;        // 0..63 (loader row)
    const int lc4  = (tid & 3) << 2;  // 0,4,8,12 (loader col group)

    float acc[8][4];
#pragma unroll
    for (int i = 0; i < 8; ++i)
#pragma unroll
        for (int j = 0; j < 4; ++j) acc[i][j] = 0.f;

    for (int seg = 0; seg < 2; ++seg) {
        const float* A = seg ? A2 : A1;
        if (A == nullptr) continue;
        const float* W = seg ? W2 : W1;
        const int K   = seg ? K2 : K1;
        const int lda = seg ? lda2 : lda1;
        const int* gat = seg ? nullptr : gather;

        size_t g0 = 0, g1 = 0;
        if (gat) {
            g0 = (size_t)gat[rowBase + lrow] * gmul;
            g1 = (size_t)gat[rowBase + lrow + 64] * gmul;
        }
        const float* ar0 = A + (size_t)(rowBase + lrow) * lda + g0;
        const float* ar1 = A + (size_t)(rowBase + lrow + 64) * lda + g1;
        const float* wr  = W + (size_t)(colBase + lrow) * K;

        for (int k0 = 0; k0 < K; k0 += BK) {
            float4 a0 = *(const float4*)(ar0 + k0 + lc4);
            float4 a1 = *(const float4*)(ar1 + k0 + lc4);
            float4 w0 = *(const float4*)(wr  + k0 + lc4);
            __syncthreads();
#pragma unroll
            for (int j = 0; j < 4; ++j) {
                As[(lc4 + j) * LDA_S + lrow]      = ((const float*)&a0)[j];
                As[(lc4 + j) * LDA_S + lrow + 64] = ((const float*)&a1)[j];
                Bs[(lc4 + j) * LDB_S + lrow]      = ((const float*)&w0)[j];
            }
            __syncthreads();
#pragma unroll
            for (int kk = 0; kk < BK; ++kk) {
                float4 av0 = *(const float4*)&As[kk * LDA_S + ty * 8];
                float4 av1 = *(const float4*)&As[kk * LDA_S + ty * 8 + 4];
                float4 bv  = *(const float4*)&Bs[kk * LDB_S + tx * 4];
                const float* ap  = (const float*)&av0;
                const float* ap2 = (const float*)&av1;
                const float* bp  = (const float*)&bv;
#pragma unroll
                for (int i = 0; i < 4; ++i)
#pragma unroll
                    for (int j = 0; j < 4; ++j) {
                        acc[i][j]     += ap[i]  * bp[j];
                        acc[i + 4][j] += ap2[i] * bp[j];
                    }
            }
        }
    }

    float4 bb = make_float4(0.f, 0.f, 0.f, 0.f);
    if (bias) bb = *(const float4*)(bias + colBase + tx * 4);
#pragma unroll
    for (int i = 0; i < 8; ++i) {
        int row = rowBase + ty * 8 + i;
        float4 o;
        o.x = acc[i][0] + bb.x;
        o.y = acc[i][1] + bb.y;
        o.z = acc[i][2] + bb.z;
        o.w = acc[i][3] + bb.w;
        *(float4*)(C + (size_t)row * ldc + colBase + tx * 4) = o;
    }
}

// ---------------------------------------------------------------------------
// LSTM elementwise: gates (B,4H) layout [i|f|g|o], update h,c.
// czero=1 -> treat c_in as 0 (first encoder step; h,c may be poison).
// ---------------------------------------------------------------------------
__global__ __launch_bounds__(256) void lstm_update(const float* __restrict__ gates,
                                                   float* __restrict__ h,
                                                   float* __restrict__ c,
                                                   int czero) {
    int idx = blockIdx.x * 256 + threadIdx.x;   // < B*H = 2,097,152
    int b = idx >> 9, j = idx & 511;
    const float* gb = gates + (size_t)b * H4;
    float gi = gb[j];
    float gf = gb[Hdim + j];
    float gg = gb[2 * Hdim + j];
    float go = gb[3 * Hdim + j];
    float si = 1.f / (1.f + expf(-gi));
    float sf = 1.f / (1.f + expf(-gf));
    float so = 1.f / (1.f + expf(-go));
    float cn = si * tanhf(gg) + (czero ? 0.f : sf * c[idx]);
    c[idx] = cn;
    h[idx] = so * tanhf(cn);
}

// ---------------------------------------------------------------------------
// Attention + log-softmax + argmax + state update. One block per batch row.
// logits[s] = 10 * sum_h Vec2[h]*tanh(qp[b,h]+u2[b,s,h]) - 1e8*mask[b,s]
// ---------------------------------------------------------------------------
__global__ __launch_bounds__(256) void attn_step(const float* __restrict__ qp,
                                                 const float* __restrict__ u2,
                                                 const float* __restrict__ Vec2,
                                                 float* __restrict__ mask,
                                                 float* __restrict__ ll_ws,
                                                 int* __restrict__ nxt,
                                                 float* __restrict__ out_map,
                                                 float* __restrict__ out_ll,
                                                 int step, int node) {
    const int b = blockIdx.x;
    __shared__ float qpS[Hdim];
    __shared__ float vS[Hdim];
    __shared__ float logitS[Sseq];
    const int tid = threadIdx.x;
    qpS[tid]       = qp[(size_t)b * Hdim + tid];
    qpS[tid + 256] = qp[(size_t)b * Hdim + 256 + tid];
    vS[tid]        = Vec2[tid];
    vS[tid + 256]  = Vec2[256 + tid];
    __syncthreads();

    const int wave = tid >> 6, lane = tid & 63;
    for (int si = 0; si < 4; ++si) {
        int s = wave * 4 + si;
        const float* u2p = u2 + ((size_t)b * Sseq + s) * Hdim;
        float sum = 0.f;
#pragma unroll
        for (int i = 0; i < 8; ++i) {
            int hh = lane + i * 64;
            sum += vS[hh] * tanhf(qpS[hh] + u2p[hh]);
        }
        for (int off = 32; off > 0; off >>= 1) sum += __shfl_down(sum, off);
        if (lane == 0) {
            float pen = step ? mask[b * Sseq + s] * 1e8f : 0.f;
            logitS[s] = 10.f * sum - pen;
        }
    }
    __syncthreads();

    if (tid == 0) {
        float mx = logitS[0];
        int am = 0;
        for (int s = 1; s < Sseq; ++s)
            if (logitS[s] > mx) { mx = logitS[s]; am = s; }  // first-max tie-break
        float se = 0.f;
        for (int s = 0; s < Sseq; ++s) se += expf(logitS[s] - mx);
        float lp = -logf(se);                 // log_p of the argmax entry
        float llv = (step ? ll_ws[b] : 0.f) + lp;
        ll_ws[b] = llv;
        out_ll[b] = llv;
        nxt[b] = am;
        if (step == 0) {
            for (int s = 0; s < Sseq; ++s) mask[b * Sseq + s] = (s == am) ? 1.f : 0.f;
        } else {
            mask[b * Sseq + am] += 1.f;
        }
        out_map[b * Sseq + am] = (float)node;  // mapping scatter, float output
    }
}

// ---------------------------------------------------------------------------
extern "C" void kernel_launch(void* const* d_in, const int* in_sizes, int n_in,
                              void* d_out, int out_size, void* d_ws, size_t ws_size,
                              hipStream_t stream) {
    const float* x       = (const float*)d_in[0];
    const float* emb_W   = (const float*)d_in[1];
    const float* enc_Wih = (const float*)d_in[2];
    const float* enc_Whh = (const float*)d_in[3];
    const float* enc_b   = (const float*)d_in[4];
    const float* dec_Wih = (const float*)d_in[5];
    const float* dec_Whh = (const float*)d_in[6];
    const float* dec_b   = (const float*)d_in[7];
    const float* Wq2     = (const float*)d_in[8];
    const float* bq2     = (const float*)d_in[9];
    const float* Wref2   = (const float*)d_in[10];
    const float* bref2   = (const float*)d_in[11];
    const float* Vec2    = (const float*)d_in[12];
    const float* dec0    = (const float*)d_in[13];

    // workspace layout (fp32 words) — ~190 MB total
    float* ws    = (float*)d_ws;
    float* u2    = ws;                                   // B*S*H = 33,554,432
    float* gates = u2 + (size_t)Bsz * Sseq * Hdim;       // B*4H  =  8,388,608
    float* h     = gates + (size_t)Bsz * H4;             // B*H
    float* c     = h + (size_t)Bsz * Hdim;               // B*H
    float* qp    = c + (size_t)Bsz * Hdim;               // B*H
    float* mask  = qp + (size_t)Bsz * Hdim;              // B*S
    float* ll    = mask + (size_t)Bsz * Sseq;            // B
    int*   nxt   = (int*)(ll + Bsz);                     // B
    float* encE  = (float*)(nxt + Bsz);                  // 4H*G = 262,144
    float* decE  = encE + (size_t)H4 * Gdim;             // 4H*G
    float* v0b   = decE + (size_t)H4 * Gdim;             // 4H

    float* out_map = (float*)d_out;                      // B*P floats
    float* out_ll  = out_map + (size_t)Bsz * Psteps;     // B floats

    static const int nodes[Psteps] = {0,0,0,0, 1,1,1,1, 2,2,2,2, 3,3,3,3};

    // 0) fold emb_W into LSTM input weights; fold dec_input0 into step-0 bias
    fold_kernel<<<H4, Gdim, 0, stream>>>(enc_Wih, dec_Wih, emb_W, dec_b, dec0,
                                         encE, decE, v0b);

    const dim3 gGates(H4 / BN, Bsz / BM);     // (32,32)
    const dim3 gH(Hdim / BN, Bsz / BM);       // (8,32)

    // 1) encoder: 16 LSTM steps; u2 slice computed incrementally from h
    for (int t = 0; t < Sseq; ++t) {
        gemm_fused<<<gGates, 256, 0, stream>>>(
            x + t * Gdim, Sseq * Gdim, Gdim, encE, nullptr, 0,
            (t ? h : nullptr), Hdim, Hdim, enc_Whh,
            enc_b, gates, H4);
        lstm_update<<<(Bsz * Hdim) / 256, 256, 0, stream>>>(gates, h, c, t == 0);
        gemm_fused<<<gH, 256, 0, stream>>>(
            nullptr, 0, 0, nullptr, nullptr, 0,
            h, Hdim, Hdim, Wref2,
            bref2, u2 + t * Hdim, Sseq * Hdim);
    }

    // 2) decoder: 16 autoregressive steps
    for (int p = 0; p < Psteps; ++p) {
        if (p == 0) {
            gemm_fused<<<gGates, 256, 0, stream>>>(
                nullptr, 0, 0, nullptr, nullptr, 0,
                h, Hdim, Hdim, dec_Whh,
                v0b, gates, H4);
        } else {
            gemm_fused<<<gGates, 256, 0, stream>>>(
                x, Sseq * Gdim, Gdim, decE, nxt, Gdim,
                h, Hdim, Hdim, dec_Whh,
                dec_b, gates, H4);
        }
        lstm_update<<<(Bsz * Hdim) / 256, 256, 0, stream>>>(gates, h, c, 0);
        gemm_fused<<<gH, 256, 0, stream>>>(
            nullptr, 0, 0, nullptr, nullptr, 0,
            h, Hdim, Hdim, Wq2,
            bq2, qp, Hdim);
        attn_step<<<Bsz, 256, 0, stream>>>(qp, u2, Vec2, mask, ll, nxt,
                                           out_map, out_ll, p, nodes[p]);
    }
}

// Round 2
// 6260.345 us; speedup vs baseline: 1.1451x; 1.1451x over previous
//
#include <hip/hip_runtime.h>
#include <cstddef>

// Problem constants
#define Bsz  4096
#define Sseq 16
#define Gdim 128
#define Edim 256
#define Hdim 512
#define H4   2048
#define Psteps 16
#define BK   16

// ---------------------------------------------------------------------------
// Fold kernel.
//  - encE/decE = (Wih @ emb_W) with GATE-INTERLEAVED rows: out row c = j*4+gate
//  - encWhhI/decWhhI = Whh rows reordered to the same interleaving
//  - encBI/decBI = biases interleaved; v0bI = dec bias + dec_Wih@dec_input0
// ---------------------------------------------------------------------------
__global__ void fold_kernel(const float* __restrict__ encWih,
                            const float* __restrict__ encWhh,
                            const float* __restrict__ enc_b,
                            const float* __restrict__ decWih,
                            const float* __restrict__ decWhh,
                            const float* __restrict__ dec_b,
                            const float* __restrict__ embW,
                            const float* __restrict__ dec0,
                            float* __restrict__ encE, float* __restrict__ encWhhI,
                            float* __restrict__ encBI,
                            float* __restrict__ decE, float* __restrict__ decWhhI,
                            float* __restrict__ decBI, float* __restrict__ v0bI) {
    const int o = blockIdx.x;            // original row 0..2047 (gate*512 + j)
    const int gate = o >> 9, j = o & 511;
    const int c = j * 4 + gate;          // interleaved row
    const int g = threadIdx.x;           // 0..127
    float se = 0.f, sd = 0.f;
    for (int e = 0; e < Edim; ++e) {
        float w = embW[e * Gdim + g];
        se += encWih[(size_t)o * Edim + e] * w;
        sd += decWih[(size_t)o * Edim + e] * w;
    }
    encE[(size_t)c * Gdim + g] = se;
    decE[(size_t)c * Gdim + g] = sd;
    for (int k = g; k < Hdim; k += Gdim) {
        encWhhI[(size_t)c * Hdim + k] = encWhh[(size_t)o * Hdim + k];
        decWhhI[(size_t)c * Hdim + k] = decWhh[(size_t)o * Hdim + k];
    }
    if (g == 0) {
        encBI[c] = enc_b[o];
        decBI[c] = dec_b[o];
        float s = dec_b[o];
        for (int e = 0; e < Edim; ++e) s += decWih[(size_t)o * Edim + e] * dec0[e];
        v0bI[c] = s;
    }
}

// ---------------------------------------------------------------------------
// Tiled fp32 GEMM, C[N x Mo] = A1@W1^T (+gather) + A2@W2^T, 256 threads.
// Wave layout: 4 waves as 2x2 over BM x BN; lane 8x8; thread tile TM x TN.
// All LDS reads are broadcast/2-way (conflict-free); staging writes conflict-
// free; global->reg prefetch of the next k-tile overlaps the FMA loop.
// Column blocks with colBase >= split form an "aux" section: K2-only GEMM
// against W3/bias3 into C3 (used for the hoisted Wref2*h projection).
// FUSE: LSTM epilogue (gate-interleaved cols) writing h_out/c_out directly.
// ---------------------------------------------------------------------------
template<int BM, int BN, int TM, int TN, bool FUSE>
__global__ __launch_bounds__(256, 2) void gemm2(
    const float* __restrict__ A1, int lda1, int K1,
    const float* __restrict__ W1,
    const int* __restrict__ gather, int gmul,
    const float* __restrict__ A2, int lda2, int K2,
    const float* __restrict__ W2,
    const float* __restrict__ bias,
    float* __restrict__ C, int ldc,
    int split,
    const float* __restrict__ W3, const float* __restrict__ bias3,
    float* __restrict__ C3, int ldc3,
    const float* __restrict__ c_in, float* __restrict__ h_out,
    float* __restrict__ c_out, int czero)
{
    __shared__ float As[BK][BM];
    __shared__ float Bs[BK][BN];
    const int tid = threadIdx.x;
    const int rowBase = blockIdx.y * BM;
    const int colBase = blockIdx.x * BN;
    const bool aux = (colBase >= split);

    const int wv = tid >> 6;
    const int waveX = wv & 1, waveY = wv >> 1;
    const int lane = tid & 63;
    const int lx = lane & 7, ly = lane >> 3;
    const int rOff = waveY * (BM / 2) + ly * TM;
    const int cOff = waveX * (BN / 2) + lx * TN;

    // staging assignment
    constexpr int NA = BM / 64;              // float4 per thread (A)
    constexpr int NB = BN / 64;
    const int ra = tid & (BM - 1);
    const int ka = (tid / BM) * (BM / 16);   // BM=128: {0,8}; BM=64: {0,4,8,12}
    const int rb = tid & (BN - 1);
    const int kb = (tid / BN) * (BN / 16);

    float4 aR[NA], bR[NB];

    auto stageA = [&](int kt) {
        const float* p;
        if (kt < K1) {
            size_t go = gather ? (size_t)gather[rowBase + ra] * gmul : 0;
            p = A1 + (size_t)(rowBase + ra) * lda1 + go + kt + ka;
        } else {
            p = A2 + (size_t)(rowBase + ra) * lda2 + (kt - K1) + ka;
        }
#pragma unroll
        for (int ii = 0; ii < NA; ++ii) aR[ii] = *(const float4*)(p + 4 * ii);
    };
    auto stageB = [&](int kt) {
        const float* p;
        if (aux) {
            p = W3 + (size_t)(colBase - split + rb) * K2 + (kt - K1) + kb;
        } else if (kt < K1) {
            p = W1 + (size_t)(colBase + rb) * K1 + kt + kb;
        } else {
            p = W2 + (size_t)(colBase + rb) * K2 + (kt - K1) + kb;
        }
#pragma unroll
        for (int ii = 0; ii < NB; ++ii) bR[ii] = *(const float4*)(p + 4 * ii);
    };

    float acc[TM][TN];
#pragma unroll
    for (int i = 0; i < TM; ++i)
#pragma unroll
        for (int j = 0; j < TN; ++j) acc[i][j] = 0.f;

    const int KT = K1 + K2;
    int kt0 = aux ? K1 : 0;
    stageA(kt0); stageB(kt0);

    for (int kt = kt0; kt < KT; kt += BK) {
        __syncthreads();
#pragma unroll
        for (int ii = 0; ii < NA; ++ii) {
            As[ka + 4 * ii + 0][ra] = aR[ii].x;
            As[ka + 4 * ii + 1][ra] = aR[ii].y;
            As[ka + 4 * ii + 2][ra] = aR[ii].z;
            As[ka + 4 * ii + 3][ra] = aR[ii].w;
        }
#pragma unroll
        for (int ii = 0; ii < NB; ++ii) {
            Bs[kb + 4 * ii + 0][rb] = bR[ii].x;
            Bs[kb + 4 * ii + 1][rb] = bR[ii].y;
            Bs[kb + 4 * ii + 2][rb] = bR[ii].z;
            Bs[kb + 4 * ii + 3][rb] = bR[ii].w;
        }
        __syncthreads();
        if (kt + BK < KT) { stageA(kt + BK); stageB(kt + BK); }

#pragma unroll
        for (int kk = 0; kk < BK; ++kk) {
            float a[TM], b[TN];
#pragma unroll
            for (int ii = 0; ii < TM / 4; ++ii)
                *(float4*)&a[4 * ii] = *(const float4*)&As[kk][rOff + 4 * ii];
#pragma unroll
            for (int ii = 0; ii < TN / 4; ++ii)
                *(float4*)&b[4 * ii] = *(const float4*)&Bs[kk][cOff + 4 * ii];
#pragma unroll
            for (int i = 0; i < TM; ++i)
#pragma unroll
                for (int j = 0; j < TN; ++j) acc[i][j] += a[i] * b[j];
        }
    }

    if (FUSE && !aux) {
        float bb[TN];
#pragma unroll
        for (int ii = 0; ii < TN / 4; ++ii)
            *(float4*)&bb[4 * ii] = *(const float4*)(bias + colBase + cOff + 4 * ii);
        const int jBase = (colBase + cOff) >> 2;   // first j; TN/4 j's per thread
#pragma unroll
        for (int i = 0; i < TM; ++i) {
            const int row = rowBase + rOff + i;
#pragma unroll
            for (int jj = 0; jj < TN / 4; ++jj) {
                float gi = acc[i][jj * 4 + 0] + bb[jj * 4 + 0];
                float gf = acc[i][jj * 4 + 1] + bb[jj * 4 + 1];
                float gg = acc[i][jj * 4 + 2] + bb[jj * 4 + 2];
                float go = acc[i][jj * 4 + 3] + bb[jj * 4 + 3];
                float si = 1.f / (1.f + expf(-gi));
                float sf = 1.f / (1.f + expf(-gf));
                float so = 1.f / (1.f + expf(-go));
                const int j = jBase + jj;
                float co = czero ? 0.f : c_in[(size_t)row * Hdim + j];
                float cn = si * tanhf(gg) + sf * co;
                c_out[(size_t)row * Hdim + j] = cn;
                h_out[(size_t)row * Hdim + j] = so * tanhf(cn);
            }
        }
    } else {
        const float* bs = aux ? bias3 : bias;
        float* Cp = aux ? C3 : C;
        const int ld = aux ? ldc3 : ldc;
        const int cb = (aux ? colBase - split : colBase) + cOff;
        float bb[TN];
#pragma unroll
        for (int ii = 0; ii < TN / 4; ++ii)
            *(float4*)&bb[4 * ii] = *(const float4*)(bs + cb + 4 * ii);
#pragma unroll
        for (int i = 0; i < TM; ++i) {
            const int row = rowBase + rOff + i;
#pragma unroll
            for (int jj = 0; jj < TN / 4; ++jj) {
                float4 o;
                o.x = acc[i][jj * 4 + 0] + bb[jj * 4 + 0];
                o.y = acc[i][jj * 4 + 1] + bb[jj * 4 + 1];
                o.z = acc[i][jj * 4 + 2] + bb[jj * 4 + 2];
                o.w = acc[i][jj * 4 + 3] + bb[jj * 4 + 3];
                *(float4*)(Cp + (size_t)row * ld + cb + 4 * jj) = o;
            }
        }
    }
}

// ---------------------------------------------------------------------------
// Attention + log-softmax + argmax + state update (unchanged from round 1).
// ---------------------------------------------------------------------------
__global__ __launch_bounds__(256) void attn_step(const float* __restrict__ qp,
                                                 const float* __restrict__ u2,
                                                 const float* __restrict__ Vec2,
                                                 float* __restrict__ mask,
                                                 float* __restrict__ ll_ws,
                                                 int* __restrict__ nxt,
                                                 float* __restrict__ out_map,
                                                 float* __restrict__ out_ll,
                                                 int step, int node) {
    const int b = blockIdx.x;
    __shared__ float qpS[Hdim];
    __shared__ float vS[Hdim];
    __shared__ float logitS[Sseq];
    const int tid = threadIdx.x;
    qpS[tid]       = qp[(size_t)b * Hdim + tid];
    qpS[tid + 256] = qp[(size_t)b * Hdim + 256 + tid];
    vS[tid]        = Vec2[tid];
    vS[tid + 256]  = Vec2[256 + tid];
    __syncthreads();

    const int wave = tid >> 6, lane = tid & 63;
    for (int si = 0; si < 4; ++si) {
        int s = wave * 4 + si;
        const float* u2p = u2 + ((size_t)b * Sseq + s) * Hdim;
        float sum = 0.f;
#pragma unroll
        for (int i = 0; i < 8; ++i) {
            int hh = lane + i * 64;
            sum += vS[hh] * tanhf(qpS[hh] + u2p[hh]);
        }
        for (int off = 32; off > 0; off >>= 1) sum += __shfl_down(sum, off);
        if (lane == 0) {
            float pen = step ? mask[b * Sseq + s] * 1e8f : 0.f;
            logitS[s] = 10.f * sum - pen;
        }
    }
    __syncthreads();

    if (tid == 0) {
        float mx = logitS[0];
        int am = 0;
        for (int s = 1; s < Sseq; ++s)
            if (logitS[s] > mx) { mx = logitS[s]; am = s; }
        float se = 0.f;
        for (int s = 0; s < Sseq; ++s) se += expf(logitS[s] - mx);
        float lp = -logf(se);
        float llv = (step ? ll_ws[b] : 0.f) + lp;
        ll_ws[b] = llv;
        out_ll[b] = llv;
        nxt[b] = am;
        if (step == 0) {
            for (int s = 0; s < Sseq; ++s) mask[b * Sseq + s] = (s == am) ? 1.f : 0.f;
        } else {
            mask[b * Sseq + am] += 1.f;
        }
        out_map[b * Sseq + am] = (float)node;
    }
}

// ---------------------------------------------------------------------------
extern "C" void kernel_launch(void* const* d_in, const int* in_sizes, int n_in,
                              void* d_out, int out_size, void* d_ws, size_t ws_size,
                              hipStream_t stream) {
    const float* x       = (const float*)d_in[0];
    const float* emb_W   = (const float*)d_in[1];
    const float* enc_Wih = (const float*)d_in[2];
    const float* enc_Whh = (const float*)d_in[3];
    const float* enc_b   = (const float*)d_in[4];
    const float* dec_Wih = (const float*)d_in[5];
    const float* dec_Whh = (const float*)d_in[6];
    const float* dec_b   = (const float*)d_in[7];
    const float* Wq2     = (const float*)d_in[8];
    const float* bq2     = (const float*)d_in[9];
    const float* Wref2   = (const float*)d_in[10];
    const float* bref2   = (const float*)d_in[11];
    const float* Vec2    = (const float*)d_in[12];
    const float* dec0    = (const float*)d_in[13];

    // workspace layout (fp32 words) — ~187 MB
    float* ws      = (float*)d_ws;
    float* u2      = ws;                                   // B*S*H
    float* h0      = u2 + (size_t)Bsz * Sseq * Hdim;       // B*H each
    float* c0      = h0 + (size_t)Bsz * Hdim;
    float* h1      = c0 + (size_t)Bsz * Hdim;
    float* c1      = h1 + (size_t)Bsz * Hdim;
    float* qp      = c1 + (size_t)Bsz * Hdim;
    float* mask    = qp + (size_t)Bsz * Hdim;              // B*S
    float* ll      = mask + (size_t)Bsz * Sseq;            // B
    int*   nxt     = (int*)(ll + Bsz);                     // B
    float* encE    = (float*)(nxt + Bsz);                  // 2048*128
    float* decE    = encE + (size_t)H4 * Gdim;
    float* encWhhI = decE + (size_t)H4 * Gdim;             // 2048*512
    float* decWhhI = encWhhI + (size_t)H4 * Hdim;
    float* encBI   = decWhhI + (size_t)H4 * Hdim;          // 2048 each
    float* decBI   = encBI + H4;
    float* v0bI    = decBI + H4;

    float* out_map = (float*)d_out;                        // B*P floats
    float* out_ll  = out_map + (size_t)Bsz * Psteps;       // B floats

    static const int nodes[Psteps] = {0,0,0,0, 1,1,1,1, 2,2,2,2, 3,3,3,3};
    const int BIG = 1 << 30;

    fold_kernel<<<H4, Gdim, 0, stream>>>(enc_Wih, enc_Whh, enc_b,
                                         dec_Wih, dec_Whh, dec_b,
                                         emb_W, dec0,
                                         encE, encWhhI, encBI,
                                         decE, decWhhI, decBI, v0bI);

    // ---- encoder: 16 fused LSTM steps; step t>=1 also computes u2[t-1] ----
    for (int t = 0; t < Sseq; ++t) {
        float* ho = (t & 1) ? h0 : h1;
        float* co = (t & 1) ? c0 : c1;
        const float* hi = (t & 1) ? h1 : h0;
        const float* ci = (t & 1) ? c1 : c0;
        if (t == 0) {
            gemm2<128,128,8,8,true><<<dim3(16,32), 256, 0, stream>>>(
                x, Sseq * Gdim, Gdim, encE, nullptr, 0,
                nullptr, 0, 0, nullptr,
                encBI, nullptr, 0,
                BIG, nullptr, nullptr, nullptr, 0,
                co /*unused*/, ho, co, 1);
        } else {
            gemm2<128,128,8,8,true><<<dim3(20,32), 256, 0, stream>>>(
                x + t * Gdim, Sseq * Gdim, Gdim, encE, nullptr, 0,
                hi, Hdim, Hdim, encWhhI,
                encBI, nullptr, 0,
                H4, Wref2, bref2, u2 + (size_t)(t - 1) * Hdim, Sseq * Hdim,
                ci, ho, co, 0);
        }
    }

    // ---- decoder: 16 autoregressive steps; p=0 also computes u2[15] ----
    for (int p = 0; p < Psteps; ++p) {
        const int u = Sseq + p;
        float* ho = (u & 1) ? h0 : h1;
        float* co = (u & 1) ? c0 : c1;
        const float* hi = (u & 1) ? h1 : h0;
        const float* ci = (u & 1) ? c1 : c0;
        if (p == 0) {
            gemm2<128,128,8,8,true><<<dim3(20,32), 256, 0, stream>>>(
                nullptr, 0, 0, nullptr, nullptr, 0,
                hi, Hdim, Hdim, decWhhI,
                v0bI, nullptr, 0,
                H4, Wref2, bref2, u2 + (size_t)15 * Hdim, Sseq * Hdim,
                ci, ho, co, 0);
        } else {
            gemm2<128,128,8,8,true><<<dim3(16,32), 256, 0, stream>>>(
                x, Sseq * Gdim, Gdim, decE, nxt, Gdim,
                hi, Hdim, Hdim, decWhhI,
                decBI, nullptr, 0,
                BIG, nullptr, nullptr, nullptr, 0,
                ci, ho, co, 0);
        }
        gemm2<64,64,4,4,false><<<dim3(8,64), 256, 0, stream>>>(
            nullptr, 0, 0, nullptr, nullptr, 0,
            ho, Hdim, Hdim, Wq2,
            bq2, qp, Hdim,
            BIG, nullptr, nullptr, nullptr, 0,
            nullptr, nullptr, nullptr, 0);
        attn_step<<<Bsz, 256, 0, stream>>>(qp, u2, Vec2, mask, ll, nxt,
                                           out_map, out_ll, p, nodes[p]);
    }
}

// Round 3
// 6132.259 us; speedup vs baseline: 1.1690x; 1.0209x over previous
//
#include <hip/hip_runtime.h>
#include <cstddef>

// Problem constants
#define Bsz  4096
#define Sseq 16
#define Gdim 128
#define Edim 256
#define Hdim 512
#define H4   2048
#define Psteps 16
#define BK   16

// ---------------------------------------------------------------------------
// Fold kernel.
//  - encE/decE = (Wih @ emb_W) with GATE-INTERLEAVED rows: out row c = j*4+gate
//  - encWhhI/decWhhI = Whh rows reordered to the same interleaving
//  - encBI/decBI = biases interleaved; v0bI = dec bias + dec_Wih@dec_input0
// ---------------------------------------------------------------------------
__global__ void fold_kernel(const float* __restrict__ encWih,
                            const float* __restrict__ encWhh,
                            const float* __restrict__ enc_b,
                            const float* __restrict__ decWih,
                            const float* __restrict__ decWhh,
                            const float* __restrict__ dec_b,
                            const float* __restrict__ embW,
                            const float* __restrict__ dec0,
                            float* __restrict__ encE, float* __restrict__ encWhhI,
                            float* __restrict__ encBI,
                            float* __restrict__ decE, float* __restrict__ decWhhI,
                            float* __restrict__ decBI, float* __restrict__ v0bI) {
    const int o = blockIdx.x;            // original row 0..2047 (gate*512 + j)
    const int gate = o >> 9, j = o & 511;
    const int c = j * 4 + gate;          // interleaved row
    const int g = threadIdx.x;           // 0..127
    float se = 0.f, sd = 0.f;
    for (int e = 0; e < Edim; ++e) {
        float w = embW[e * Gdim + g];
        se += encWih[(size_t)o * Edim + e] * w;
        sd += decWih[(size_t)o * Edim + e] * w;
    }
    encE[(size_t)c * Gdim + g] = se;
    decE[(size_t)c * Gdim + g] = sd;
    for (int k = g; k < Hdim; k += Gdim) {
        encWhhI[(size_t)c * Hdim + k] = encWhh[(size_t)o * Hdim + k];
        decWhhI[(size_t)c * Hdim + k] = decWhh[(size_t)o * Hdim + k];
    }
    if (g == 0) {
        encBI[c] = enc_b[o];
        decBI[c] = dec_b[o];
        float s = dec_b[o];
        for (int e = 0; e < Edim; ++e) s += decWih[(size_t)o * Edim + e] * dec0[e];
        v0bI[c] = s;
    }
}

// ---------------------------------------------------------------------------
// Tiled fp32 GEMM, C[N x Mo] = A1@W1^T (+gather) + A2@W2^T, 256 threads.
// Wave layout: 4 waves as 2x2 over BM x BN; lane 8x8; thread tile TM x TN.
// BM=128/BN=64 -> grid 1024-1280 blocks (4-6 blocks/CU co-resident: the
// round-2 config was 640 blocks = 2.5/CU -> 15% occupancy, tail-bound).
// Column blocks with colBase >= split form an "aux" section: K2-only GEMM
// against W3/bias3 into C3 (the hoisted Wref2*h projection).
// FUSE: LSTM epilogue (gate-interleaved cols) writing h_out/c_out directly.
// ---------------------------------------------------------------------------
template<int BM, int BN, int TM, int TN, bool FUSE>
__global__ __launch_bounds__(256, 4) void gemm2(
    const float* __restrict__ A1, int lda1, int K1,
    const float* __restrict__ W1,
    const int* __restrict__ gather, int gmul,
    const float* __restrict__ A2, int lda2, int K2,
    const float* __restrict__ W2,
    const float* __restrict__ bias,
    float* __restrict__ C, int ldc,
    int split,
    const float* __restrict__ W3, const float* __restrict__ bias3,
    float* __restrict__ C3, int ldc3,
    const float* __restrict__ c_in, float* __restrict__ h_out,
    float* __restrict__ c_out, int czero)
{
    __shared__ float As[BK][BM];
    __shared__ float Bs[BK][BN];
    const int tid = threadIdx.x;
    const int rowBase = blockIdx.y * BM;
    const int colBase = blockIdx.x * BN;
    const bool aux = (colBase >= split);

    const int wv = tid >> 6;
    const int waveX = wv & 1, waveY = wv >> 1;
    const int lane = tid & 63;
    const int lx = lane & 7, ly = lane >> 3;
    const int rOff = waveY * (BM / 2) + ly * TM;
    const int cOff = waveX * (BN / 2) + lx * TN;

    // staging assignment
    constexpr int NA = BM / 64;              // float4 per thread (A)
    constexpr int NB = BN / 64;
    const int ra = tid & (BM - 1);
    const int ka = (tid / BM) * (BM / 16);
    const int rb = tid & (BN - 1);
    const int kb = (tid / BN) * (BN / 16);

    // loop-invariant row pointers (gather hoisted out of the k-loop)
    size_t g0 = 0;
    if (gather) g0 = (size_t)gather[rowBase + ra] * gmul;
    const float* arow1 = A1 ? (A1 + (size_t)(rowBase + ra) * lda1 + g0 + ka) : nullptr;
    const float* arow2 = A2 ? (A2 + (size_t)(rowBase + ra) * lda2 + ka) : nullptr;
    const float* brow1 = W1 ? (W1 + (size_t)(colBase + rb) * K1 + kb) : nullptr;
    const float* brow2 = W2 ? (W2 + (size_t)(colBase + rb) * K2 + kb) : nullptr;
    const float* brow3 = W3 ? (W3 + (size_t)(colBase - split + rb) * K2 + kb) : nullptr;

    float4 aR[NA], bR[NB];

    auto stageA = [&](int kt) {
        const float* p = (kt < K1) ? (arow1 + kt) : (arow2 + (kt - K1));
#pragma unroll
        for (int ii = 0; ii < NA; ++ii) aR[ii] = *(const float4*)(p + 4 * ii);
    };
    auto stageB = [&](int kt) {
        const float* p;
        if (aux)            p = brow3 + (kt - K1);
        else if (kt < K1)   p = brow1 + kt;
        else                p = brow2 + (kt - K1);
#pragma unroll
        for (int ii = 0; ii < NB; ++ii) bR[ii] = *(const float4*)(p + 4 * ii);
    };

    float acc[TM][TN];
#pragma unroll
    for (int i = 0; i < TM; ++i)
#pragma unroll
        for (int j = 0; j < TN; ++j) acc[i][j] = 0.f;

    const int KT = K1 + K2;
    int kt0 = aux ? K1 : 0;
    stageA(kt0); stageB(kt0);

    for (int kt = kt0; kt < KT; kt += BK) {
        __syncthreads();
#pragma unroll
        for (int ii = 0; ii < NA; ++ii) {
            As[ka + 4 * ii + 0][ra] = aR[ii].x;
            As[ka + 4 * ii + 1][ra] = aR[ii].y;
            As[ka + 4 * ii + 2][ra] = aR[ii].z;
            As[ka + 4 * ii + 3][ra] = aR[ii].w;
        }
#pragma unroll
        for (int ii = 0; ii < NB; ++ii) {
            Bs[kb + 4 * ii + 0][rb] = bR[ii].x;
            Bs[kb + 4 * ii + 1][rb] = bR[ii].y;
            Bs[kb + 4 * ii + 2][rb] = bR[ii].z;
            Bs[kb + 4 * ii + 3][rb] = bR[ii].w;
        }
        __syncthreads();
        if (kt + BK < KT) { stageA(kt + BK); stageB(kt + BK); }

#pragma unroll
        for (int kk = 0; kk < BK; ++kk) {
            float a[TM], b[TN];
#pragma unroll
            for (int ii = 0; ii < TM / 4; ++ii)
                *(float4*)&a[4 * ii] = *(const float4*)&As[kk][rOff + 4 * ii];
#pragma unroll
            for (int ii = 0; ii < TN / 4; ++ii)
                *(float4*)&b[4 * ii] = *(const float4*)&Bs[kk][cOff + 4 * ii];
#pragma unroll
            for (int i = 0; i < TM; ++i)
#pragma unroll
                for (int j = 0; j < TN; ++j) acc[i][j] += a[i] * b[j];
        }
    }

    if (FUSE && !aux) {
        float bb[TN];
#pragma unroll
        for (int ii = 0; ii < TN / 4; ++ii)
            *(float4*)&bb[4 * ii] = *(const float4*)(bias + colBase + cOff + 4 * ii);
        const int jBase = (colBase + cOff) >> 2;
#pragma unroll
        for (int i = 0; i < TM; ++i) {
            const int row = rowBase + rOff + i;
#pragma unroll
            for (int jj = 0; jj < TN / 4; ++jj) {
                float gi = acc[i][jj * 4 + 0] + bb[jj * 4 + 0];
                float gf = acc[i][jj * 4 + 1] + bb[jj * 4 + 1];
                float gg = acc[i][jj * 4 + 2] + bb[jj * 4 + 2];
                float go = acc[i][jj * 4 + 3] + bb[jj * 4 + 3];
                float si = 1.f / (1.f + expf(-gi));
                float sf = 1.f / (1.f + expf(-gf));
                float so = 1.f / (1.f + expf(-go));
                const int j = jBase + jj;
                float co = czero ? 0.f : c_in[(size_t)row * Hdim + j];
                float cn = si * tanhf(gg) + sf * co;
                c_out[(size_t)row * Hdim + j] = cn;
                h_out[(size_t)row * Hdim + j] = so * tanhf(cn);
            }
        }
    } else {
        const float* bs = aux ? bias3 : bias;
        float* Cp = aux ? C3 : C;
        const int ld = aux ? ldc3 : ldc;
        const int cb = (aux ? colBase - split : colBase) + cOff;
        float bb[TN];
#pragma unroll
        for (int ii = 0; ii < TN / 4; ++ii)
            *(float4*)&bb[4 * ii] = *(const float4*)(bs + cb + 4 * ii);
#pragma unroll
        for (int i = 0; i < TM; ++i) {
            const int row = rowBase + rOff + i;
#pragma unroll
            for (int jj = 0; jj < TN / 4; ++jj) {
                float4 o;
                o.x = acc[i][jj * 4 + 0] + bb[jj * 4 + 0];
                o.y = acc[i][jj * 4 + 1] + bb[jj * 4 + 1];
                o.z = acc[i][jj * 4 + 2] + bb[jj * 4 + 2];
                o.w = acc[i][jj * 4 + 3] + bb[jj * 4 + 3];
                *(float4*)(Cp + (size_t)row * ld + cb + 4 * jj) = o;
            }
        }
    }
}

// ---------------------------------------------------------------------------
// Attention + log-softmax + argmax + state update.
// ---------------------------------------------------------------------------
__global__ __launch_bounds__(256) void attn_step(const float* __restrict__ qp,
                                                 const float* __restrict__ u2,
                                                 const float* __restrict__ Vec2,
                                                 float* __restrict__ mask,
                                                 float* __restrict__ ll_ws,
                                                 int* __restrict__ nxt,
                                                 float* __restrict__ out_map,
                                                 float* __restrict__ out_ll,
                                                 int step, int node) {
    const int b = blockIdx.x;
    __shared__ float qpS[Hdim];
    __shared__ float vS[Hdim];
    __shared__ float logitS[Sseq];
    const int tid = threadIdx.x;
    qpS[tid]       = qp[(size_t)b * Hdim + tid];
    qpS[tid + 256] = qp[(size_t)b * Hdim + 256 + tid];
    vS[tid]        = Vec2[tid];
    vS[tid + 256]  = Vec2[256 + tid];
    __syncthreads();

    const int wave = tid >> 6, lane = tid & 63;
    for (int si = 0; si < 4; ++si) {
        int s = wave * 4 + si;
        const float* u2p = u2 + ((size_t)b * Sseq + s) * Hdim;
        float sum = 0.f;
#pragma unroll
        for (int i = 0; i < 8; ++i) {
            int hh = lane + i * 64;
            sum += vS[hh] * tanhf(qpS[hh] + u2p[hh]);
        }
        for (int off = 32; off > 0; off >>= 1) sum += __shfl_down(sum, off);
        if (lane == 0) {
            float pen = step ? mask[b * Sseq + s] * 1e8f : 0.f;
            logitS[s] = 10.f * sum - pen;
        }
    }
    __syncthreads();

    if (tid == 0) {
        float mx = logitS[0];
        int am = 0;
        for (int s = 1; s < Sseq; ++s)
            if (logitS[s] > mx) { mx = logitS[s]; am = s; }
        float se = 0.f;
        for (int s = 0; s < Sseq; ++s) se += expf(logitS[s] - mx);
        float lp = -logf(se);
        float llv = (step ? ll_ws[b] : 0.f) + lp;
        ll_ws[b] = llv;
        out_ll[b] = llv;
        nxt[b] = am;
        if (step == 0) {
            for (int s = 0; s < Sseq; ++s) mask[b * Sseq + s] = (s == am) ? 1.f : 0.f;
        } else {
            mask[b * Sseq + am] += 1.f;
        }
        out_map[b * Sseq + am] = (float)node;
    }
}

// ---------------------------------------------------------------------------
extern "C" void kernel_launch(void* const* d_in, const int* in_sizes, int n_in,
                              void* d_out, int out_size, void* d_ws, size_t ws_size,
                              hipStream_t stream) {
    const float* x       = (const float*)d_in[0];
    const float* emb_W   = (const float*)d_in[1];
    const float* enc_Wih = (const float*)d_in[2];
    const float* enc_Whh = (const float*)d_in[3];
    const float* enc_b   = (const float*)d_in[4];
    const float* dec_Wih = (const float*)d_in[5];
    const float* dec_Whh = (const float*)d_in[6];
    const float* dec_b   = (const float*)d_in[7];
    const float* Wq2     = (const float*)d_in[8];
    const float* bq2     = (const float*)d_in[9];
    const float* Wref2   = (const float*)d_in[10];
    const float* bref2   = (const float*)d_in[11];
    const float* Vec2    = (const float*)d_in[12];
    const float* dec0    = (const float*)d_in[13];

    // workspace layout (fp32 words) — ~187 MB
    float* ws      = (float*)d_ws;
    float* u2      = ws;                                   // B*S*H
    float* h0      = u2 + (size_t)Bsz * Sseq * Hdim;       // B*H each
    float* c0      = h0 + (size_t)Bsz * Hdim;
    float* h1      = c0 + (size_t)Bsz * Hdim;
    float* c1      = h1 + (size_t)Bsz * Hdim;
    float* qp      = c1 + (size_t)Bsz * Hdim;
    float* mask    = qp + (size_t)Bsz * Hdim;              // B*S
    float* ll      = mask + (size_t)Bsz * Sseq;            // B
    int*   nxt     = (int*)(ll + Bsz);                     // B
    float* encE    = (float*)(nxt + Bsz);                  // 2048*128
    float* decE    = encE + (size_t)H4 * Gdim;
    float* encWhhI = decE + (size_t)H4 * Gdim;             // 2048*512
    float* decWhhI = encWhhI + (size_t)H4 * Hdim;
    float* encBI   = decWhhI + (size_t)H4 * Hdim;          // 2048 each
    float* decBI   = encBI + H4;
    float* v0bI    = decBI + H4;

    float* out_map = (float*)d_out;                        // B*P floats
    float* out_ll  = out_map + (size_t)Bsz * Psteps;       // B floats

    static const int nodes[Psteps] = {0,0,0,0, 1,1,1,1, 2,2,2,2, 3,3,3,3};
    const int BIG = 1 << 30;

    fold_kernel<<<H4, Gdim, 0, stream>>>(enc_Wih, enc_Whh, enc_b,
                                         dec_Wih, dec_Whh, dec_b,
                                         emb_W, dec0,
                                         encE, encWhhI, encBI,
                                         decE, decWhhI, decBI, v0bI);

    // ---- encoder: 16 fused LSTM steps; step t>=1 also computes u2[t-1] ----
    for (int t = 0; t < Sseq; ++t) {
        float* ho = (t & 1) ? h0 : h1;
        float* co = (t & 1) ? c0 : c1;
        const float* hi = (t & 1) ? h1 : h0;
        const float* ci = (t & 1) ? c1 : c0;
        if (t == 0) {
            gemm2<128,64,8,4,true><<<dim3(32,32), 256, 0, stream>>>(
                x, Sseq * Gdim, Gdim, encE, nullptr, 0,
                nullptr, 0, 0, nullptr,
                encBI, nullptr, 0,
                BIG, nullptr, nullptr, nullptr, 0,
                co /*unused*/, ho, co, 1);
        } else {
            gemm2<128,64,8,4,true><<<dim3(40,32), 256, 0, stream>>>(
                x + t * Gdim, Sseq * Gdim, Gdim, encE, nullptr, 0,
                hi, Hdim, Hdim, encWhhI,
                encBI, nullptr, 0,
                H4, Wref2, bref2, u2 + (size_t)(t - 1) * Hdim, Sseq * Hdim,
                ci, ho, co, 0);
        }
    }

    // ---- decoder: 16 autoregressive steps; p=0 also computes u2[15] ----
    for (int p = 0; p < Psteps; ++p) {
        const int u = Sseq + p;
        float* ho = (u & 1) ? h0 : h1;
        float* co = (u & 1) ? c0 : c1;
        const float* hi = (u & 1) ? h1 : h0;
        const float* ci = (u & 1) ? c1 : c0;
        if (p == 0) {
            gemm2<128,64,8,4,true><<<dim3(40,32), 256, 0, stream>>>(
                nullptr, 0, 0, nullptr, nullptr, 0,
                hi, Hdim, Hdim, decWhhI,
                v0bI, nullptr, 0,
                H4, Wref2, bref2, u2 + (size_t)15 * Hdim, Sseq * Hdim,
                ci, ho, co, 0);
        } else {
            gemm2<128,64,8,4,true><<<dim3(32,32), 256, 0, stream>>>(
                x, Sseq * Gdim, Gdim, decE, nxt, Gdim,
                hi, Hdim, Hdim, decWhhI,
                decBI, nullptr, 0,
                BIG, nullptr, nullptr, nullptr, 0,
                ci, ho, co, 0);
        }
        gemm2<64,64,4,4,false><<<dim3(8,64), 256, 0, stream>>>(
            nullptr, 0, 0, nullptr, nullptr, 0,
            ho, Hdim, Hdim, Wq2,
            bq2, qp, Hdim,
            BIG, nullptr, nullptr, nullptr, 0,
            nullptr, nullptr, nullptr, 0);
        attn_step<<<Bsz, 256, 0, stream>>>(qp, u2, Vec2, mask, ll, nxt,
                                           out_map, out_ll, p, nodes[p]);
    }
}